// Round 1
// baseline (634.219 us; speedup 1.0000x reference)
//
#include <hip/hip_runtime.h>
#include <cstdint>
#include <cstddef>

// Problem constants (from reference): N=50000 nodes, E=800000 edges,
// F_in=512, H=128, C=64. Dims hard-coded for unrolling; N,E read from sizes.
constexpr int FIN = 512;
constexpr int HD  = 128;
constexpr int CD  = 64;

// ---------------- CSR build: histogram -> scan -> scatter ----------------

__global__ __launch_bounds__(256) void hist_kernel(const int* __restrict__ dst, int E,
                                                   int* __restrict__ cnt) {
  int i = blockIdx.x * 256 + threadIdx.x;
  if (i < E) atomicAdd(&cnt[dst[i]], 1);
}

__global__ __launch_bounds__(1024) void scan_kernel(const int* __restrict__ cnt,
                                                    int* __restrict__ off,
                                                    int* __restrict__ cur, int n) {
  __shared__ int sh[1024];
  int tid = threadIdx.x;
  int chunk = (n + 1023) >> 10;
  int base = tid * chunk;
  int total = 0;
  for (int j = 0; j < chunk; ++j) {
    int idx = base + j;
    if (idx < n) total += cnt[idx];
  }
  sh[tid] = total;
  __syncthreads();
  for (int o = 1; o < 1024; o <<= 1) {
    int v = (tid >= o) ? sh[tid - o] : 0;
    __syncthreads();
    sh[tid] += v;
    __syncthreads();
  }
  int run = sh[tid] - total;  // exclusive prefix
  for (int j = 0; j < chunk; ++j) {
    int idx = base + j;
    if (idx < n) {
      off[idx] = run;
      cur[idx] = run;
      run += cnt[idx];
    }
  }
}

__global__ __launch_bounds__(256) void scatter_kernel(const int* __restrict__ src,
                                                      const int* __restrict__ dst,
                                                      const float* __restrict__ ew, int E,
                                                      int* __restrict__ cur,
                                                      int* __restrict__ ssrc,
                                                      float* __restrict__ sw) {
  int i = blockIdx.x * 256 + threadIdx.x;
  if (i < E) {
    int d = dst[i];
    int p = atomicAdd(&cur[d], 1);
    ssrc[p] = src[i];
    sw[p]   = ew[i];
  }
}

// ---------------- GEMM1: h1[M,128] = x[M,512] @ W1[512,128] (fp32) ----------------
// 64x128 tile per 256-thread block; K-chunk 16; thread = 4 rows x 8 cols.
// As stored [k][m] (transposed) pad 68; Bs [k][n] pad 132 -> all fragment
// reads are b128 with same-address broadcast across the wave (conflict-free).

__global__ __launch_bounds__(256) void gemm1_kernel(const float* __restrict__ x,
                                                    const float* __restrict__ W1,
                                                    float* __restrict__ h1, int M) {
  __shared__ float As[16][68];
  __shared__ float Bs[16][132];
  const int t    = threadIdx.x;
  const int m0   = blockIdx.x * 64;
  const int tx   = t & 15;        // col group: c0 = tx*8
  const int ty   = t >> 4;        // row group: r0 = ty*4
  const int lrow = t >> 2;        // A-load row within tile (0..63)
  const int lk4  = (t & 3) << 2;  // A-load k start within chunk
  const int grow = m0 + lrow;
  const bool rowok = grow < M;
  const float* xrow = x + (size_t)grow * FIN;

  float acc[4][8];
#pragma unroll
  for (int i = 0; i < 4; ++i)
#pragma unroll
    for (int j = 0; j < 8; ++j) acc[i][j] = 0.f;

  const int i0 = t * 4;
  const int r0i = i0 >> 7, c0i = i0 & 127;
  const int i1 = i0 + 1024;
  const int r1i = i1 >> 7, c1i = i1 & 127;

  for (int k0 = 0; k0 < FIN; k0 += 16) {
    float4 av = make_float4(0.f, 0.f, 0.f, 0.f);
    if (rowok) av = *(const float4*)(xrow + k0 + lk4);
    float4 bv0 = *(const float4*)(W1 + (size_t)(k0 + r0i) * HD + c0i);
    float4 bv1 = *(const float4*)(W1 + (size_t)(k0 + r1i) * HD + c1i);
    __syncthreads();  // previous chunk's reads done before overwrite
    As[lk4 + 0][lrow] = av.x;
    As[lk4 + 1][lrow] = av.y;
    As[lk4 + 2][lrow] = av.z;
    As[lk4 + 3][lrow] = av.w;
    *(float4*)&Bs[r0i][c0i] = bv0;
    *(float4*)&Bs[r1i][c1i] = bv1;
    __syncthreads();
#pragma unroll
    for (int kk = 0; kk < 16; ++kk) {
      float4 a   = *(const float4*)&As[kk][ty << 2];
      float4 b0  = *(const float4*)&Bs[kk][tx << 3];
      float4 b1v = *(const float4*)&Bs[kk][(tx << 3) + 4];
      float am[4] = {a.x, a.y, a.z, a.w};
      float bn[8] = {b0.x, b0.y, b0.z, b0.w, b1v.x, b1v.y, b1v.z, b1v.w};
#pragma unroll
      for (int i = 0; i < 4; ++i)
#pragma unroll
        for (int j = 0; j < 8; ++j) acc[i][j] = fmaf(am[i], bn[j], acc[i][j]);
    }
  }
#pragma unroll
  for (int i = 0; i < 4; ++i) {
    int r = m0 + (ty << 2) + i;
    if (r < M) {
      float4 o0 = {acc[i][0], acc[i][1], acc[i][2], acc[i][3]};
      float4 o1 = {acc[i][4], acc[i][5], acc[i][6], acc[i][7]};
      *(float4*)(h1 + (size_t)r * HD + (tx << 3)) = o0;
      *(float4*)(h1 + (size_t)r * HD + (tx << 3) + 4) = o1;
    }
  }
}

// ---------------- agg1 + bias + relu + dropout -> h[N,128] ----------------
// One block per node, 128 threads (one per feature). CSR gather, no atomics.

__global__ __launch_bounds__(128) void agg1_kernel(const float* __restrict__ h1,
                                                   const float* __restrict__ b1,
                                                   const float* __restrict__ dm,
                                                   const int* __restrict__ off,
                                                   const int* __restrict__ cnt,
                                                   const int* __restrict__ ssrc,
                                                   const float* __restrict__ sw,
                                                   float* __restrict__ h) {
  int node  = blockIdx.x;
  int f     = threadIdx.x;
  int start = off[node];
  int deg   = cnt[node];
  float acc = 0.f;
  for (int e = 0; e < deg; ++e) {
    int   s  = ssrc[start + e];
    float wv = sw[start + e];
    acc = fmaf(h1[(size_t)s * HD + f], wv, acc);
  }
  acc = fmaxf(acc + b1[f], 0.f);
  float keep = (dm[(size_t)node * HD + f] >= 0.5f) ? 2.0f : 0.0f;
  h[(size_t)node * HD + f] = acc * keep;
}

// ---------------- GEMM2: h2[M,64] = h[M,128] @ W2[128,64] (fp32) ----------------
// Same structure, 64x64 tile, thread = 4x4.

__global__ __launch_bounds__(256) void gemm2_kernel(const float* __restrict__ h,
                                                    const float* __restrict__ W2,
                                                    float* __restrict__ h2, int M) {
  __shared__ float As[16][68];
  __shared__ float Bs[16][68];
  const int t    = threadIdx.x;
  const int m0   = blockIdx.x * 64;
  const int tx   = t & 15;        // c0 = tx*4
  const int ty   = t >> 4;        // r0 = ty*4
  const int lrow = t >> 2;
  const int lk4  = (t & 3) << 2;
  const int grow = m0 + lrow;
  const bool rowok = grow < M;
  const float* hrow = h + (size_t)grow * HD;

  float acc[4][4];
#pragma unroll
  for (int i = 0; i < 4; ++i)
#pragma unroll
    for (int j = 0; j < 4; ++j) acc[i][j] = 0.f;

  const int i0 = t * 4;
  const int r0i = i0 >> 6, c0i = i0 & 63;

  for (int k0 = 0; k0 < HD; k0 += 16) {
    float4 av = make_float4(0.f, 0.f, 0.f, 0.f);
    if (rowok) av = *(const float4*)(hrow + k0 + lk4);
    float4 bv0 = *(const float4*)(W2 + (size_t)(k0 + r0i) * CD + c0i);
    __syncthreads();
    As[lk4 + 0][lrow] = av.x;
    As[lk4 + 1][lrow] = av.y;
    As[lk4 + 2][lrow] = av.z;
    As[lk4 + 3][lrow] = av.w;
    *(float4*)&Bs[r0i][c0i] = bv0;
    __syncthreads();
#pragma unroll
    for (int kk = 0; kk < 16; ++kk) {
      float4 a = *(const float4*)&As[kk][ty << 2];
      float4 b = *(const float4*)&Bs[kk][tx << 2];
      float am[4] = {a.x, a.y, a.z, a.w};
      float bn[4] = {b.x, b.y, b.z, b.w};
#pragma unroll
      for (int i = 0; i < 4; ++i)
#pragma unroll
        for (int j = 0; j < 4; ++j) acc[i][j] = fmaf(am[i], bn[j], acc[i][j]);
    }
  }
#pragma unroll
  for (int i = 0; i < 4; ++i) {
    int r = m0 + (ty << 2) + i;
    if (r < M) {
      float4 o0 = {acc[i][0], acc[i][1], acc[i][2], acc[i][3]};
      *(float4*)(h2 + (size_t)r * CD + (tx << 2)) = o0;
    }
  }
}

// ---------------- agg2 + bias + log_softmax -> out[N,64] ----------------
// One wave per node; lane = class. Width-64 shuffle reductions.

__global__ __launch_bounds__(64) void agg2_kernel(const float* __restrict__ h2,
                                                  const float* __restrict__ b2,
                                                  const int* __restrict__ off,
                                                  const int* __restrict__ cnt,
                                                  const int* __restrict__ ssrc,
                                                  const float* __restrict__ sw,
                                                  float* __restrict__ out) {
  int node  = blockIdx.x;
  int c     = threadIdx.x;
  int start = off[node];
  int deg   = cnt[node];
  float acc = b2[c];
  for (int e = 0; e < deg; ++e) {
    int   s  = ssrc[start + e];
    float wv = sw[start + e];
    acc = fmaf(h2[(size_t)s * CD + c], wv, acc);
  }
  float m = acc;
#pragma unroll
  for (int o = 32; o > 0; o >>= 1) m = fmaxf(m, __shfl_xor(m, o, 64));
  float ex = __expf(acc - m);
  float ssum = ex;
#pragma unroll
  for (int o = 32; o > 0; o >>= 1) ssum += __shfl_xor(ssum, o, 64);
  out[(size_t)node * CD + c] = (acc - m) - __logf(ssum);
}

// ---------------- launch ----------------

extern "C" void kernel_launch(void* const* d_in, const int* in_sizes, int n_in,
                              void* d_out, int out_size, void* d_ws, size_t ws_size,
                              hipStream_t stream) {
  const float* x  = (const float*)d_in[0];
  const float* ew = (const float*)d_in[1];
  const float* W1 = (const float*)d_in[2];
  const float* b1 = (const float*)d_in[3];
  const float* W2 = (const float*)d_in[4];
  const float* b2 = (const float*)d_in[5];
  const float* dm = (const float*)d_in[6];
  const int*   ei = (const int*)d_in[7];
  float* out = (float*)d_out;

  const int E = in_sizes[1];          // edge_weight count
  const int N = in_sizes[6] / HD;     // drop_mask is [N,128]
  const int* srcp = ei;
  const int* dstp = ei + E;

  uint8_t* w = (uint8_t*)d_ws;
  size_t o = 0;
  auto alloc = [&](size_t bytes) -> void* {
    void* p = w + o;
    o = (o + bytes + 255) & ~(size_t)255;
    return p;
  };
  int*   off  = (int*)alloc((size_t)N * 4);
  int*   cnt  = (int*)alloc((size_t)N * 4);
  int*   cur  = (int*)alloc((size_t)N * 4);
  int*   ssrc = (int*)alloc((size_t)E * 4);
  float* sw   = (float*)alloc((size_t)E * 4);
  float* h1   = (float*)alloc((size_t)N * HD * 4);
  float* h    = (float*)alloc((size_t)N * HD * 4);
  float* h2   = (float*)alloc((size_t)N * CD * 4);

  hipMemsetAsync(cnt, 0, (size_t)N * 4, stream);
  hist_kernel<<<(E + 255) / 256, 256, 0, stream>>>(dstp, E, cnt);
  scan_kernel<<<1, 1024, 0, stream>>>(cnt, off, cur, N);
  scatter_kernel<<<(E + 255) / 256, 256, 0, stream>>>(srcp, dstp, ew, E, cur, ssrc, sw);
  gemm1_kernel<<<(N + 63) / 64, 256, 0, stream>>>(x, W1, h1, N);
  agg1_kernel<<<N, 128, 0, stream>>>(h1, b1, dm, off, cnt, ssrc, sw, h);
  gemm2_kernel<<<(N + 63) / 64, 256, 0, stream>>>(h, W2, h2, N);
  agg2_kernel<<<N, 64, 0, stream>>>(h2, b2, off, cnt, ssrc, sw, out);
}

// Round 2
// 476.248 us; speedup vs baseline: 1.3317x; 1.3317x over previous
//
#include <hip/hip_runtime.h>
#include <cstdint>
#include <cstddef>

// N=50000 nodes, E=800000 edges, F_in=512, H=128, C=64.
constexpr int FIN = 512;
constexpr int HD  = 128;
constexpr int CD  = 64;

typedef __attribute__((ext_vector_type(8))) short short8;   // 8 bf16 = 4 VGPRs
typedef __attribute__((ext_vector_type(4))) float f32x4;    // MFMA acc

__device__ inline unsigned short f2bf(float f) {  // RNE fp32->bf16
  unsigned int u = __float_as_uint(f);
  u += 0x7fffu + ((u >> 16) & 1u);
  return (unsigned short)(u >> 16);
}

// ---------------- CSR build ----------------

__global__ __launch_bounds__(256) void hist_kernel(const int* __restrict__ dst, int E,
                                                   int* __restrict__ cnt) {
  int i = blockIdx.x * 256 + threadIdx.x;
  if (i < E) atomicAdd(&cnt[dst[i]], 1);
}

// phase A: per-block (2048 elements) sums, coalesced
__global__ __launch_bounds__(256) void scan_a(const int* __restrict__ cnt,
                                              int* __restrict__ bs, int n) {
  __shared__ int sh[256];
  int t = threadIdx.x;
  int base = blockIdx.x * 2048;
  int s = 0;
#pragma unroll
  for (int j = 0; j < 8; ++j) {
    int idx = base + j * 256 + t;
    if (idx < n) s += cnt[idx];
  }
  sh[t] = s;
  __syncthreads();
  for (int o = 128; o > 0; o >>= 1) {
    if (t < o) sh[t] += sh[t + o];
    __syncthreads();
  }
  if (t == 0) bs[blockIdx.x] = sh[0];
}

// phase B: exclusive scan of block sums (nb <= 64), one wave
__global__ __launch_bounds__(64) void scan_b(const int* __restrict__ bs,
                                             int* __restrict__ bo, int nb) {
  int t = threadIdx.x;
  int v = (t < nb) ? bs[t] : 0;
  int own = v;
#pragma unroll
  for (int o = 1; o < 64; o <<= 1) {
    int u = __shfl_up(v, o, 64);
    if (t >= o) v += u;
  }
  if (t < nb) bo[t] = v - own;
}

// phase C: per-block local exclusive scan + global offset -> off, cur
__global__ __launch_bounds__(256) void scan_c(const int* __restrict__ cnt,
                                              const int* __restrict__ bo,
                                              int* __restrict__ off,
                                              int* __restrict__ cur, int n) {
  __shared__ int sh[256];
  int t = threadIdx.x;
  int base = blockIdx.x * 2048 + t * 8;
  int v[8];
  int local = 0;
#pragma unroll
  for (int j = 0; j < 8; ++j) {
    v[j] = (base + j < n) ? cnt[base + j] : 0;
    local += v[j];
  }
  sh[t] = local;
  __syncthreads();
  for (int o = 1; o < 256; o <<= 1) {
    int u = (t >= o) ? sh[t - o] : 0;
    __syncthreads();
    sh[t] += u;
    __syncthreads();
  }
  int run = sh[t] - local + bo[blockIdx.x];
#pragma unroll
  for (int j = 0; j < 8; ++j) {
    if (base + j < n) { off[base + j] = run; cur[base + j] = run; }
    run += v[j];
  }
}

__global__ __launch_bounds__(256) void scatter_kernel(const int* __restrict__ src,
                                                      const int* __restrict__ dst,
                                                      const float* __restrict__ ew, int E,
                                                      int* __restrict__ cur,
                                                      int* __restrict__ ssrc,
                                                      float* __restrict__ sw) {
  int i = blockIdx.x * 256 + threadIdx.x;
  if (i < E) {
    int d = dst[i];
    int p = atomicAdd(&cur[d], 1);
    ssrc[p] = src[i];
    sw[p]   = ew[i];
  }
}

// ---------------- W1 -> bf16 transposed [n][k] ----------------

__global__ __launch_bounds__(256) void w1t_prep(const float* __restrict__ W1,
                                                unsigned short* __restrict__ w1t) {
  int idx = blockIdx.x * 256 + threadIdx.x;  // FIN*HD threads, coalesced read
  int k = idx >> 7;   // /HD
  int n = idx & 127;
  w1t[(size_t)n * FIN + k] = f2bf(W1[idx]);
}

// ---------------- GEMM1 (MFMA bf16): h1[M,128] = x[M,512] @ W1 ----------------
// 64x128 output tile / block (256 thr = 4 waves). Wave w: 16 rows x 128 cols
// = 1 m-tile x 8 n-tiles of 16x16x32 MFMA. BK=32, 16 K-iters.
// A layout (verified): m=lane&15, k=quad*8+j. C/D: col=lane&15, row=quad*4+r.
// LDS rows padded to 40 ushorts (20 banks) -> <=2-way conflicts (free).

__global__ __launch_bounds__(256) void gemm1_mfma(const float* __restrict__ x,
                                                  const unsigned short* __restrict__ w1t,
                                                  float* __restrict__ h1, int M) {
  __shared__ unsigned short As[64][40];
  __shared__ unsigned short Bs[128][40];
  const int t    = threadIdx.x;
  const int wave = t >> 6;
  const int lane = t & 63;
  const int l15  = lane & 15;
  const int quad = lane >> 4;
  const int m0   = blockIdx.x * 64;

  const int ra = t >> 2;         // A staging row 0..63
  const int ka = (t & 3) * 8;    // A staging k {0,8,16,24}
  const int rb = t >> 1;         // B staging row 0..127
  const int kb = (t & 1) * 16;   // B staging k {0,16}

  const bool aok = (m0 + ra) < M;
  const float* xrow = x + (size_t)(m0 + ra) * FIN + ka;
  const unsigned short* brow = w1t + (size_t)rb * FIN + kb;

  f32x4 acc[8];
#pragma unroll
  for (int i = 0; i < 8; ++i) acc[i] = (f32x4)0.f;

  for (int k0 = 0; k0 < FIN; k0 += 32) {
    float4 f0 = make_float4(0.f, 0.f, 0.f, 0.f);
    float4 f1 = f0;
    if (aok) {
      f0 = *(const float4*)(xrow + k0);
      f1 = *(const float4*)(xrow + k0 + 4);
    }
    uint4 b0 = *(const uint4*)(brow + k0);
    uint4 b1 = *(const uint4*)(brow + k0 + 8);
    __syncthreads();  // prior iter's frag reads complete
    unsigned short tmp[8];
    tmp[0] = f2bf(f0.x); tmp[1] = f2bf(f0.y); tmp[2] = f2bf(f0.z); tmp[3] = f2bf(f0.w);
    tmp[4] = f2bf(f1.x); tmp[5] = f2bf(f1.y); tmp[6] = f2bf(f1.z); tmp[7] = f2bf(f1.w);
    *(uint4*)&As[ra][ka] = *(const uint4*)tmp;
    *(uint4*)&Bs[rb][kb] = b0;
    *(uint4*)&Bs[rb][kb + 8] = b1;
    __syncthreads();
    short8 af = *(const short8*)&As[wave * 16 + l15][quad * 8];
#pragma unroll
    for (int nt = 0; nt < 8; ++nt) {
      short8 bf = *(const short8*)&Bs[nt * 16 + l15][quad * 8];
      acc[nt] = __builtin_amdgcn_mfma_f32_16x16x32_bf16(af, bf, acc[nt], 0, 0, 0);
    }
  }
  const int row0 = m0 + wave * 16 + quad * 4;
#pragma unroll
  for (int r = 0; r < 4; ++r) {
    int row = row0 + r;
    if (row < M) {
      float* orow = h1 + (size_t)row * HD + l15;
#pragma unroll
      for (int nt = 0; nt < 8; ++nt) orow[nt * 16] = acc[nt][r];
    }
  }
}

// ---------------- agg1 + bias + relu + dropout -> h[N,128] ----------------

__global__ __launch_bounds__(128) void agg1_kernel(const float* __restrict__ h1,
                                                   const float* __restrict__ b1,
                                                   const float* __restrict__ dm,
                                                   const int* __restrict__ off,
                                                   const int* __restrict__ cnt,
                                                   const int* __restrict__ ssrc,
                                                   const float* __restrict__ sw,
                                                   float* __restrict__ h) {
  int node  = blockIdx.x;
  int f     = threadIdx.x;
  int start = off[node];
  int deg   = cnt[node];
  float acc = 0.f;
  for (int e = 0; e < deg; ++e) {
    int   s  = ssrc[start + e];
    float wv = sw[start + e];
    acc = fmaf(h1[(size_t)s * HD + f], wv, acc);
  }
  acc = fmaxf(acc + b1[f], 0.f);
  float keep = (dm[(size_t)node * HD + f] >= 0.5f) ? 2.0f : 0.0f;
  h[(size_t)node * HD + f] = acc * keep;
}

// ---------------- GEMM2 (fp32): h2[M,64] = h[M,128] @ W2[128,64] ----------------

__global__ __launch_bounds__(256) void gemm2_kernel(const float* __restrict__ h,
                                                    const float* __restrict__ W2,
                                                    float* __restrict__ h2, int M) {
  __shared__ float As[16][68];
  __shared__ float Bs[16][68];
  const int t    = threadIdx.x;
  const int m0   = blockIdx.x * 64;
  const int tx   = t & 15;
  const int ty   = t >> 4;
  const int lrow = t >> 2;
  const int lk4  = (t & 3) << 2;
  const int grow = m0 + lrow;
  const bool rowok = grow < M;
  const float* hrow = h + (size_t)grow * HD;

  float acc[4][4];
#pragma unroll
  for (int i = 0; i < 4; ++i)
#pragma unroll
    for (int j = 0; j < 4; ++j) acc[i][j] = 0.f;

  const int i0 = t * 4;
  const int r0i = i0 >> 6, c0i = i0 & 63;

  for (int k0 = 0; k0 < HD; k0 += 16) {
    float4 av = make_float4(0.f, 0.f, 0.f, 0.f);
    if (rowok) av = *(const float4*)(hrow + k0 + lk4);
    float4 bv0 = *(const float4*)(W2 + (size_t)(k0 + r0i) * CD + c0i);
    __syncthreads();
    As[lk4 + 0][lrow] = av.x;
    As[lk4 + 1][lrow] = av.y;
    As[lk4 + 2][lrow] = av.z;
    As[lk4 + 3][lrow] = av.w;
    *(float4*)&Bs[r0i][c0i] = bv0;
    __syncthreads();
#pragma unroll
    for (int kk = 0; kk < 16; ++kk) {
      float4 a = *(const float4*)&As[kk][ty << 2];
      float4 b = *(const float4*)&Bs[kk][tx << 2];
      float am[4] = {a.x, a.y, a.z, a.w};
      float bn[4] = {b.x, b.y, b.z, b.w};
#pragma unroll
      for (int i = 0; i < 4; ++i)
#pragma unroll
        for (int j = 0; j < 4; ++j) acc[i][j] = fmaf(am[i], bn[j], acc[i][j]);
    }
  }
#pragma unroll
  for (int i = 0; i < 4; ++i) {
    int r = m0 + (ty << 2) + i;
    if (r < M) {
      float4 o0 = {acc[i][0], acc[i][1], acc[i][2], acc[i][3]};
      *(float4*)(h2 + (size_t)r * CD + (tx << 2)) = o0;
    }
  }
}

// ---------------- agg2 + bias + log_softmax -> out[N,64] ----------------

__global__ __launch_bounds__(64) void agg2_kernel(const float* __restrict__ h2,
                                                  const float* __restrict__ b2,
                                                  const int* __restrict__ off,
                                                  const int* __restrict__ cnt,
                                                  const int* __restrict__ ssrc,
                                                  const float* __restrict__ sw,
                                                  float* __restrict__ out) {
  int node  = blockIdx.x;
  int c     = threadIdx.x;
  int start = off[node];
  int deg   = cnt[node];
  float acc = b2[c];
  for (int e = 0; e < deg; ++e) {
    int   s  = ssrc[start + e];
    float wv = sw[start + e];
    acc = fmaf(h2[(size_t)s * CD + c], wv, acc);
  }
  float m = acc;
#pragma unroll
  for (int o = 32; o > 0; o >>= 1) m = fmaxf(m, __shfl_xor(m, o, 64));
  float ex = __expf(acc - m);
  float ssum = ex;
#pragma unroll
  for (int o = 32; o > 0; o >>= 1) ssum += __shfl_xor(ssum, o, 64);
  out[(size_t)node * CD + c] = (acc - m) - __logf(ssum);
}

// ---------------- launch ----------------

extern "C" void kernel_launch(void* const* d_in, const int* in_sizes, int n_in,
                              void* d_out, int out_size, void* d_ws, size_t ws_size,
                              hipStream_t stream) {
  const float* x  = (const float*)d_in[0];
  const float* ew = (const float*)d_in[1];
  const float* W1 = (const float*)d_in[2];
  const float* b1 = (const float*)d_in[3];
  const float* W2 = (const float*)d_in[4];
  const float* b2 = (const float*)d_in[5];
  const float* dm = (const float*)d_in[6];
  const int*   ei = (const int*)d_in[7];
  float* out = (float*)d_out;

  const int E = in_sizes[1];
  const int N = in_sizes[6] / HD;
  const int* srcp = ei;
  const int* dstp = ei + E;
  const int nb = (N + 2047) / 2048;  // scan blocks (25 for N=50000, <=64)

  uint8_t* w = (uint8_t*)d_ws;
  size_t o = 0;
  auto alloc = [&](size_t bytes) -> void* {
    void* p = w + o;
    o = (o + bytes + 255) & ~(size_t)255;
    return p;
  };
  int*   off  = (int*)alloc((size_t)N * 4);
  int*   cnt  = (int*)alloc((size_t)N * 4);
  int*   cur  = (int*)alloc((size_t)N * 4);
  int*   ssrc = (int*)alloc((size_t)E * 4);
  float* sw   = (float*)alloc((size_t)E * 4);
  float* h1   = (float*)alloc((size_t)N * HD * 4);
  float* h    = (float*)alloc((size_t)N * HD * 4);
  float* h2   = (float*)alloc((size_t)N * CD * 4);
  unsigned short* w1t = (unsigned short*)alloc((size_t)FIN * HD * 2);
  int*   bsum = (int*)alloc((size_t)nb * 4);
  int*   boff = (int*)alloc((size_t)nb * 4);

  hipMemsetAsync(cnt, 0, (size_t)N * 4, stream);
  w1t_prep<<<(FIN * HD) / 256, 256, 0, stream>>>(W1, w1t);
  hist_kernel<<<(E + 255) / 256, 256, 0, stream>>>(dstp, E, cnt);
  scan_a<<<nb, 256, 0, stream>>>(cnt, bsum, N);
  scan_b<<<1, 64, 0, stream>>>(bsum, boff, nb);
  scan_c<<<nb, 256, 0, stream>>>(cnt, boff, off, cur, N);
  scatter_kernel<<<(E + 255) / 256, 256, 0, stream>>>(srcp, dstp, ew, E, cur, ssrc, sw);
  gemm1_mfma<<<(N + 63) / 64, 256, 0, stream>>>(x, w1t, h1, N);
  agg1_kernel<<<N, 128, 0, stream>>>(h1, b1, dm, off, cnt, ssrc, sw, h);
  gemm2_kernel<<<(N + 63) / 64, 256, 0, stream>>>(h, W2, h2, N);
  agg2_kernel<<<N, 64, 0, stream>>>(h2, b2, off, cnt, ssrc, sw, out);
}

// Round 3
// 397.398 us; speedup vs baseline: 1.5959x; 1.1984x over previous
//
#include <hip/hip_runtime.h>
#include <cstdint>
#include <cstddef>

// N=50000 nodes, E=800000 edges, F_in=512, H=128, C=64.
constexpr int FIN = 512;
constexpr int HD  = 128;
constexpr int CD  = 64;

typedef __attribute__((ext_vector_type(8))) short short8;   // 8 bf16 = 4 VGPRs
typedef __attribute__((ext_vector_type(4))) float f32x4;    // MFMA acc

__device__ inline unsigned short f2bf(float f) {  // RNE fp32->bf16
  unsigned int u = __float_as_uint(f);
  u += 0x7fffu + ((u >> 16) & 1u);
  return (unsigned short)(u >> 16);
}
__device__ inline float bf_lo(unsigned int v) { return __uint_as_float(v << 16); }
__device__ inline float bf_hi(unsigned int v) { return __uint_as_float(v & 0xffff0000u); }

// ---------------- CSR build ----------------

__global__ __launch_bounds__(256) void hist_kernel(const int* __restrict__ dst, int E,
                                                   int* __restrict__ cnt) {
  int i = blockIdx.x * 256 + threadIdx.x;
  if (i < E) atomicAdd(&cnt[dst[i]], 1);
}

__global__ __launch_bounds__(256) void scan_a(const int* __restrict__ cnt,
                                              int* __restrict__ bs, int n) {
  __shared__ int sh[256];
  int t = threadIdx.x;
  int base = blockIdx.x * 2048;
  int s = 0;
#pragma unroll
  for (int j = 0; j < 8; ++j) {
    int idx = base + j * 256 + t;
    if (idx < n) s += cnt[idx];
  }
  sh[t] = s;
  __syncthreads();
  for (int o = 128; o > 0; o >>= 1) {
    if (t < o) sh[t] += sh[t + o];
    __syncthreads();
  }
  if (t == 0) bs[blockIdx.x] = sh[0];
}

__global__ __launch_bounds__(64) void scan_b(const int* __restrict__ bs,
                                             int* __restrict__ bo, int nb) {
  int t = threadIdx.x;
  int v = (t < nb) ? bs[t] : 0;
  int own = v;
#pragma unroll
  for (int o = 1; o < 64; o <<= 1) {
    int u = __shfl_up(v, o, 64);
    if (t >= o) v += u;
  }
  if (t < nb) bo[t] = v - own;
}

__global__ __launch_bounds__(256) void scan_c(const int* __restrict__ cnt,
                                              const int* __restrict__ bo,
                                              int* __restrict__ off,
                                              int* __restrict__ cur, int n) {
  __shared__ int sh[256];
  int t = threadIdx.x;
  int base = blockIdx.x * 2048 + t * 8;
  int v[8];
  int local = 0;
#pragma unroll
  for (int j = 0; j < 8; ++j) {
    v[j] = (base + j < n) ? cnt[base + j] : 0;
    local += v[j];
  }
  sh[t] = local;
  __syncthreads();
  for (int o = 1; o < 256; o <<= 1) {
    int u = (t >= o) ? sh[t - o] : 0;
    __syncthreads();
    sh[t] += u;
    __syncthreads();
  }
  int run = sh[t] - local + bo[blockIdx.x];
#pragma unroll
  for (int j = 0; j < 8; ++j) {
    if (base + j < n) { off[base + j] = run; cur[base + j] = run; }
    run += v[j];
  }
}

// scatter (src, weight-bits) as int2 -> one 8B load per edge later
__global__ __launch_bounds__(256) void scatter_kernel(const int* __restrict__ src,
                                                      const int* __restrict__ dst,
                                                      const float* __restrict__ ew, int E,
                                                      int* __restrict__ cur,
                                                      int2* __restrict__ sew) {
  int i = blockIdx.x * 256 + threadIdx.x;
  if (i < E) {
    int d = dst[i];
    int p = atomicAdd(&cur[d], 1);
    sew[p] = make_int2(src[i], __float_as_int(ew[i]));
  }
}

// ---------------- W1 -> bf16 transposed [n][k] ----------------

__global__ __launch_bounds__(256) void w1t_prep(const float* __restrict__ W1,
                                                unsigned short* __restrict__ w1t) {
  int idx = blockIdx.x * 256 + threadIdx.x;
  int k = idx >> 7;
  int n = idx & 127;
  w1t[(size_t)n * FIN + k] = f2bf(W1[idx]);
}

// ---------------- GEMM1 (MFMA bf16): h1b[M,128](bf16) = x @ W1 ----------------

__global__ __launch_bounds__(256) void gemm1_mfma(const float* __restrict__ x,
                                                  const unsigned short* __restrict__ w1t,
                                                  unsigned short* __restrict__ h1b, int M) {
  __shared__ unsigned short As[64][40];
  __shared__ unsigned short Bs[128][40];
  const int t    = threadIdx.x;
  const int wave = t >> 6;
  const int lane = t & 63;
  const int l15  = lane & 15;
  const int quad = lane >> 4;
  const int m0   = blockIdx.x * 64;

  const int ra = t >> 2;
  const int ka = (t & 3) * 8;
  const int rb = t >> 1;
  const int kb = (t & 1) * 16;

  const bool aok = (m0 + ra) < M;
  const float* xrow = x + (size_t)(m0 + ra) * FIN + ka;
  const unsigned short* brow = w1t + (size_t)rb * FIN + kb;

  f32x4 acc[8];
#pragma unroll
  for (int i = 0; i < 8; ++i) acc[i] = (f32x4)0.f;

  for (int k0 = 0; k0 < FIN; k0 += 32) {
    float4 f0 = make_float4(0.f, 0.f, 0.f, 0.f);
    float4 f1 = f0;
    if (aok) {
      f0 = *(const float4*)(xrow + k0);
      f1 = *(const float4*)(xrow + k0 + 4);
    }
    uint4 b0 = *(const uint4*)(brow + k0);
    uint4 b1 = *(const uint4*)(brow + k0 + 8);
    __syncthreads();
    unsigned short tmp[8];
    tmp[0] = f2bf(f0.x); tmp[1] = f2bf(f0.y); tmp[2] = f2bf(f0.z); tmp[3] = f2bf(f0.w);
    tmp[4] = f2bf(f1.x); tmp[5] = f2bf(f1.y); tmp[6] = f2bf(f1.z); tmp[7] = f2bf(f1.w);
    *(uint4*)&As[ra][ka] = *(const uint4*)tmp;
    *(uint4*)&Bs[rb][kb] = b0;
    *(uint4*)&Bs[rb][kb + 8] = b1;
    __syncthreads();
    short8 af = *(const short8*)&As[wave * 16 + l15][quad * 8];
#pragma unroll
    for (int nt = 0; nt < 8; ++nt) {
      short8 bf = *(const short8*)&Bs[nt * 16 + l15][quad * 8];
      acc[nt] = __builtin_amdgcn_mfma_f32_16x16x32_bf16(af, bf, acc[nt], 0, 0, 0);
    }
  }
  const int row0 = m0 + wave * 16 + quad * 4;
#pragma unroll
  for (int r = 0; r < 4; ++r) {
    int row = row0 + r;
    if (row < M) {
      unsigned short* orow = h1b + (size_t)row * HD + l15;
#pragma unroll
      for (int nt = 0; nt < 8; ++nt) orow[nt * 16] = f2bf(acc[nt][r]);
    }
  }
}

// ---------------- agg1: one wave per node, 4-edge unroll, bf16 gather ----------------
// lane handles features {2*lane, 2*lane+1} via packed bf16x2 uint loads.

__global__ __launch_bounds__(256) void agg1_kernel(const unsigned int* __restrict__ h1b,
                                                   const float* __restrict__ b1,
                                                   const float* __restrict__ dm,
                                                   const int* __restrict__ off,
                                                   const int* __restrict__ cnt,
                                                   const int2* __restrict__ sew,
                                                   float* __restrict__ h, int N) {
  const int wave = threadIdx.x >> 6;
  const int lane = threadIdx.x & 63;
  const int node = blockIdx.x * 4 + wave;
  if (node >= N) return;
  const int start = off[node];
  const int deg   = cnt[node];
  const int2* ep  = sew + start;

  float a0 = 0.f, a1 = 0.f, c0 = 0.f, c1 = 0.f;
  int e = 0;
  for (; e + 4 <= deg; e += 4) {
    int2 p0 = ep[e + 0];
    int2 p1 = ep[e + 1];
    int2 p2 = ep[e + 2];
    int2 p3 = ep[e + 3];
    unsigned int v0 = h1b[(size_t)p0.x * 64 + lane];
    unsigned int v1 = h1b[(size_t)p1.x * 64 + lane];
    unsigned int v2 = h1b[(size_t)p2.x * 64 + lane];
    unsigned int v3 = h1b[(size_t)p3.x * 64 + lane];
    float w0 = __int_as_float(p0.y), w1 = __int_as_float(p1.y);
    float w2 = __int_as_float(p2.y), w3 = __int_as_float(p3.y);
    a0 = fmaf(bf_lo(v0), w0, a0); a1 = fmaf(bf_hi(v0), w0, a1);
    c0 = fmaf(bf_lo(v1), w1, c0); c1 = fmaf(bf_hi(v1), w1, c1);
    a0 = fmaf(bf_lo(v2), w2, a0); a1 = fmaf(bf_hi(v2), w2, a1);
    c0 = fmaf(bf_lo(v3), w3, c0); c1 = fmaf(bf_hi(v3), w3, c1);
  }
  for (; e < deg; ++e) {
    int2 p = ep[e];
    unsigned int v = h1b[(size_t)p.x * 64 + lane];
    float w = __int_as_float(p.y);
    a0 = fmaf(bf_lo(v), w, a0); a1 = fmaf(bf_hi(v), w, a1);
  }
  a0 += c0; a1 += c1;

  const int f0 = lane * 2;
  float2 bb = *(const float2*)(b1 + f0);
  float2 dd = *(const float2*)(dm + (size_t)node * HD + f0);
  float r0 = fmaxf(a0 + bb.x, 0.f) * ((dd.x >= 0.5f) ? 2.0f : 0.0f);
  float r1 = fmaxf(a1 + bb.y, 0.f) * ((dd.y >= 0.5f) ? 2.0f : 0.0f);
  *(float2*)(h + (size_t)node * HD + f0) = make_float2(r0, r1);
}

// ---------------- GEMM2 (fp32): h2[M,64] = h[M,128] @ W2[128,64] ----------------

__global__ __launch_bounds__(256) void gemm2_kernel(const float* __restrict__ h,
                                                    const float* __restrict__ W2,
                                                    float* __restrict__ h2, int M) {
  __shared__ float As[16][68];
  __shared__ float Bs[16][68];
  const int t    = threadIdx.x;
  const int m0   = blockIdx.x * 64;
  const int tx   = t & 15;
  const int ty   = t >> 4;
  const int lrow = t >> 2;
  const int lk4  = (t & 3) << 2;
  const int grow = m0 + lrow;
  const bool rowok = grow < M;
  const float* hrow = h + (size_t)grow * HD;

  float acc[4][4];
#pragma unroll
  for (int i = 0; i < 4; ++i)
#pragma unroll
    for (int j = 0; j < 4; ++j) acc[i][j] = 0.f;

  const int i0 = t * 4;
  const int r0i = i0 >> 6, c0i = i0 & 63;

  for (int k0 = 0; k0 < HD; k0 += 16) {
    float4 av = make_float4(0.f, 0.f, 0.f, 0.f);
    if (rowok) av = *(const float4*)(hrow + k0 + lk4);
    float4 bv0 = *(const float4*)(W2 + (size_t)(k0 + r0i) * CD + c0i);
    __syncthreads();
    As[lk4 + 0][lrow] = av.x;
    As[lk4 + 1][lrow] = av.y;
    As[lk4 + 2][lrow] = av.z;
    As[lk4 + 3][lrow] = av.w;
    *(float4*)&Bs[r0i][c0i] = bv0;
    __syncthreads();
#pragma unroll
    for (int kk = 0; kk < 16; ++kk) {
      float4 a = *(const float4*)&As[kk][ty << 2];
      float4 b = *(const float4*)&Bs[kk][tx << 2];
      float am[4] = {a.x, a.y, a.z, a.w};
      float bn[4] = {b.x, b.y, b.z, b.w};
#pragma unroll
      for (int i = 0; i < 4; ++i)
#pragma unroll
        for (int j = 0; j < 4; ++j) acc[i][j] = fmaf(am[i], bn[j], acc[i][j]);
    }
  }
#pragma unroll
  for (int i = 0; i < 4; ++i) {
    int r = m0 + (ty << 2) + i;
    if (r < M) {
      float4 o0 = {acc[i][0], acc[i][1], acc[i][2], acc[i][3]};
      *(float4*)(h2 + (size_t)r * CD + (tx << 2)) = o0;
    }
  }
}

// ---------------- agg2 + bias + log_softmax: one wave per node, 4-edge unroll ----------------

__global__ __launch_bounds__(256) void agg2_kernel(const float* __restrict__ h2,
                                                   const float* __restrict__ b2,
                                                   const int* __restrict__ off,
                                                   const int* __restrict__ cnt,
                                                   const int2* __restrict__ sew,
                                                   float* __restrict__ out, int N) {
  const int wave = threadIdx.x >> 6;
  const int c    = threadIdx.x & 63;
  const int node = blockIdx.x * 4 + wave;
  if (node >= N) return;
  const int start = off[node];
  const int deg   = cnt[node];
  const int2* ep  = sew + start;

  float acc = b2[c], acc2 = 0.f;
  int e = 0;
  for (; e + 4 <= deg; e += 4) {
    int2 p0 = ep[e + 0];
    int2 p1 = ep[e + 1];
    int2 p2 = ep[e + 2];
    int2 p3 = ep[e + 3];
    float v0 = h2[(size_t)p0.x * CD + c];
    float v1 = h2[(size_t)p1.x * CD + c];
    float v2 = h2[(size_t)p2.x * CD + c];
    float v3 = h2[(size_t)p3.x * CD + c];
    acc  = fmaf(v0, __int_as_float(p0.y), acc);
    acc2 = fmaf(v1, __int_as_float(p1.y), acc2);
    acc  = fmaf(v2, __int_as_float(p2.y), acc);
    acc2 = fmaf(v3, __int_as_float(p3.y), acc2);
  }
  for (; e < deg; ++e) {
    int2 p = ep[e];
    acc = fmaf(h2[(size_t)p.x * CD + c], __int_as_float(p.y), acc);
  }
  acc += acc2;

  float m = acc;
#pragma unroll
  for (int o = 32; o > 0; o >>= 1) m = fmaxf(m, __shfl_xor(m, o, 64));
  float ex = __expf(acc - m);
  float ssum = ex;
#pragma unroll
  for (int o = 32; o > 0; o >>= 1) ssum += __shfl_xor(ssum, o, 64);
  out[(size_t)node * CD + c] = (acc - m) - __logf(ssum);
}

// ---------------- launch ----------------

extern "C" void kernel_launch(void* const* d_in, const int* in_sizes, int n_in,
                              void* d_out, int out_size, void* d_ws, size_t ws_size,
                              hipStream_t stream) {
  const float* x  = (const float*)d_in[0];
  const float* ew = (const float*)d_in[1];
  const float* W1 = (const float*)d_in[2];
  const float* b1 = (const float*)d_in[3];
  const float* W2 = (const float*)d_in[4];
  const float* b2 = (const float*)d_in[5];
  const float* dm = (const float*)d_in[6];
  const int*   ei = (const int*)d_in[7];
  float* out = (float*)d_out;

  const int E = in_sizes[1];
  const int N = in_sizes[6] / HD;
  const int* srcp = ei;
  const int* dstp = ei + E;
  const int nb = (N + 2047) / 2048;

  uint8_t* w = (uint8_t*)d_ws;
  size_t o = 0;
  auto alloc = [&](size_t bytes) -> void* {
    void* p = w + o;
    o = (o + bytes + 255) & ~(size_t)255;
    return p;
  };
  int*   off  = (int*)alloc((size_t)N * 4);
  int*   cnt  = (int*)alloc((size_t)N * 4);
  int*   cur  = (int*)alloc((size_t)N * 4);
  int2*  sew  = (int2*)alloc((size_t)E * 8);
  unsigned short* h1b = (unsigned short*)alloc((size_t)N * HD * 2);
  float* h    = (float*)alloc((size_t)N * HD * 4);
  float* h2   = (float*)alloc((size_t)N * CD * 4);
  unsigned short* w1t = (unsigned short*)alloc((size_t)FIN * HD * 2);
  int*   bsum = (int*)alloc((size_t)nb * 4);
  int*   boff = (int*)alloc((size_t)nb * 4);

  hipMemsetAsync(cnt, 0, (size_t)N * 4, stream);
  w1t_prep<<<(FIN * HD) / 256, 256, 0, stream>>>(W1, w1t);
  hist_kernel<<<(E + 255) / 256, 256, 0, stream>>>(dstp, E, cnt);
  scan_a<<<nb, 256, 0, stream>>>(cnt, bsum, N);
  scan_b<<<1, 64, 0, stream>>>(bsum, boff, nb);
  scan_c<<<nb, 256, 0, stream>>>(cnt, boff, off, cur, N);
  scatter_kernel<<<(E + 255) / 256, 256, 0, stream>>>(srcp, dstp, ew, E, cur, sew);
  gemm1_mfma<<<(N + 63) / 64, 256, 0, stream>>>(x, w1t, h1b, N);
  agg1_kernel<<<(N + 3) / 4, 256, 0, stream>>>((const unsigned int*)h1b, b1, dm, off, cnt, sew, h, N);
  gemm2_kernel<<<(N + 63) / 64, 256, 0, stream>>>(h, W2, h2, N);
  agg2_kernel<<<(N + 3) / 4, 256, 0, stream>>>(h2, b2, off, cnt, sew, out, N);
}

// Round 5
// 372.178 us; speedup vs baseline: 1.7041x; 1.0678x over previous
//
#include <hip/hip_runtime.h>
#include <cstdint>
#include <cstddef>

// N=50000 nodes, E=800000 edges, F_in=512, H=128, C=64.
constexpr int FIN = 512;
constexpr int HD  = 128;
constexpr int CD  = 64;

typedef __attribute__((ext_vector_type(8))) short short8;   // 8 bf16 = 4 VGPRs
typedef __attribute__((ext_vector_type(4))) float f32x4;    // MFMA acc

__device__ inline unsigned short f2bf(float f) {  // RNE fp32->bf16
  unsigned int u = __float_as_uint(f);
  u += 0x7fffu + ((u >> 16) & 1u);
  return (unsigned short)(u >> 16);
}
__device__ inline float bf_lo(unsigned int v) { return __uint_as_float(v << 16); }
__device__ inline float bf_hi(unsigned int v) { return __uint_as_float(v & 0xffff0000u); }
__device__ inline float bf1(unsigned short v) { return __uint_as_float((unsigned int)v << 16); }

// ---------------- CSR build ----------------

__global__ __launch_bounds__(256) void hist_kernel(const int* __restrict__ dst, int E,
                                                   int* __restrict__ cnt) {
  int i = blockIdx.x * 256 + threadIdx.x;
  if (i < E) atomicAdd(&cnt[dst[i]], 1);
}

__global__ __launch_bounds__(256) void scan_a(const int* __restrict__ cnt,
                                              int* __restrict__ bs, int n) {
  __shared__ int sh[256];
  int t = threadIdx.x;
  int base = blockIdx.x * 2048;
  int s = 0;
#pragma unroll
  for (int j = 0; j < 8; ++j) {
    int idx = base + j * 256 + t;
    if (idx < n) s += cnt[idx];
  }
  sh[t] = s;
  __syncthreads();
  for (int o = 128; o > 0; o >>= 1) {
    if (t < o) sh[t] += sh[t + o];
    __syncthreads();
  }
  if (t == 0) bs[blockIdx.x] = sh[0];
}

__global__ __launch_bounds__(64) void scan_b(const int* __restrict__ bs,
                                             int* __restrict__ bo, int nb) {
  int t = threadIdx.x;
  int v = (t < nb) ? bs[t] : 0;
  int own = v;
#pragma unroll
  for (int o = 1; o < 64; o <<= 1) {
    int u = __shfl_up(v, o, 64);
    if (t >= o) v += u;
  }
  if (t < nb) bo[t] = v - own;
}

__global__ __launch_bounds__(256) void scan_c(const int* __restrict__ cnt,
                                              const int* __restrict__ bo,
                                              int* __restrict__ off,
                                              int* __restrict__ cur, int n) {
  __shared__ int sh[256];
  int t = threadIdx.x;
  int base = blockIdx.x * 2048 + t * 8;
  int v[8];
  int local = 0;
#pragma unroll
  for (int j = 0; j < 8; ++j) {
    v[j] = (base + j < n) ? cnt[base + j] : 0;
    local += v[j];
  }
  sh[t] = local;
  __syncthreads();
  for (int o = 1; o < 256; o <<= 1) {
    int u = (t >= o) ? sh[t - o] : 0;
    __syncthreads();
    sh[t] += u;
    __syncthreads();
  }
  int run = sh[t] - local + bo[blockIdx.x];
#pragma unroll
  for (int j = 0; j < 8; ++j) {
    if (base + j < n) { off[base + j] = run; cur[base + j] = run; }
    run += v[j];
  }
}

__global__ __launch_bounds__(256) void scatter_kernel(const int* __restrict__ src,
                                                      const int* __restrict__ dst,
                                                      const float* __restrict__ ew, int E,
                                                      int* __restrict__ cur,
                                                      int2* __restrict__ sew) {
  int i = blockIdx.x * 256 + threadIdx.x;
  if (i < E) {
    int d = dst[i];
    int p = atomicAdd(&cur[d], 1);
    sew[p] = make_int2(src[i], __float_as_int(ew[i]));
  }
}

// ---------------- weight prep: W1->[n][k] bf16, W2->[n][k] bf16 ----------------

__global__ __launch_bounds__(256) void wprep(const float* __restrict__ W1,
                                             const float* __restrict__ W2,
                                             unsigned short* __restrict__ w1t,
                                             unsigned short* __restrict__ w2t) {
  int idx = blockIdx.x * 256 + threadIdx.x;
  if (idx < FIN * HD) {
    int k = idx >> 7, n = idx & 127;
    w1t[(size_t)n * FIN + k] = f2bf(W1[idx]);
  } else {
    int j = idx - FIN * HD;
    if (j < HD * CD) {
      int k = j >> 6, n = j & 63;
      w2t[(size_t)n * HD + k] = f2bf(W2[j]);
    }
  }
}

// ---------------- GEMM1 (MFMA bf16): h1b[M,128](bf16) = x @ W1 ----------------
// 128x128 tile / 256-thr block (4 waves). Wave w: rows [32w,32w+32) = 2 m-tiles
// x 8 n-tiles of 16x16x32 -> 16 MFMA per BK=32 step.

__global__ __launch_bounds__(256) void gemm1_mfma(const float* __restrict__ x,
                                                  const unsigned short* __restrict__ w1t,
                                                  unsigned short* __restrict__ h1b, int M) {
  __shared__ unsigned short As[128][40];
  __shared__ unsigned short Bs[128][40];
  const int t    = threadIdx.x;
  const int wave = t >> 6;
  const int lane = t & 63;
  const int l15  = lane & 15;
  const int quad = lane >> 4;
  const int m0   = blockIdx.x * 128;

  const int sr = t >> 1;        // staging row 0..127 (A and B)
  const int sk = (t & 1) * 16;  // staging k: 0 or 16

  const bool aok = (m0 + sr) < M;
  const float* xrow = x + (size_t)(m0 + sr) * FIN + sk;
  const unsigned short* brow = w1t + (size_t)sr * FIN + sk;

  f32x4 acc[2][8];
#pragma unroll
  for (int i = 0; i < 2; ++i)
#pragma unroll
    for (int j = 0; j < 8; ++j) acc[i][j] = (f32x4)0.f;

  for (int k0 = 0; k0 < FIN; k0 += 32) {
    float4 a0 = make_float4(0.f, 0.f, 0.f, 0.f), a1 = a0, a2 = a0, a3 = a0;
    if (aok) {
      a0 = *(const float4*)(xrow + k0);
      a1 = *(const float4*)(xrow + k0 + 4);
      a2 = *(const float4*)(xrow + k0 + 8);
      a3 = *(const float4*)(xrow + k0 + 12);
    }
    uint4 b0 = *(const uint4*)(brow + k0);
    uint4 b1 = *(const uint4*)(brow + k0 + 8);
    __syncthreads();
    unsigned short tmp[16];
    tmp[0]  = f2bf(a0.x); tmp[1]  = f2bf(a0.y); tmp[2]  = f2bf(a0.z); tmp[3]  = f2bf(a0.w);
    tmp[4]  = f2bf(a1.x); tmp[5]  = f2bf(a1.y); tmp[6]  = f2bf(a1.z); tmp[7]  = f2bf(a1.w);
    tmp[8]  = f2bf(a2.x); tmp[9]  = f2bf(a2.y); tmp[10] = f2bf(a2.z); tmp[11] = f2bf(a2.w);
    tmp[12] = f2bf(a3.x); tmp[13] = f2bf(a3.y); tmp[14] = f2bf(a3.z); tmp[15] = f2bf(a3.w);
    *(uint4*)&As[sr][sk]     = ((const uint4*)tmp)[0];
    *(uint4*)&As[sr][sk + 8] = ((const uint4*)tmp)[1];
    *(uint4*)&Bs[sr][sk]     = b0;
    *(uint4*)&Bs[sr][sk + 8] = b1;
    __syncthreads();
    short8 af0 = *(const short8*)&As[wave * 32 + l15][quad * 8];
    short8 af1 = *(const short8*)&As[wave * 32 + 16 + l15][quad * 8];
#pragma unroll
    for (int nt = 0; nt < 8; ++nt) {
      short8 bf = *(const short8*)&Bs[nt * 16 + l15][quad * 8];
      acc[0][nt] = __builtin_amdgcn_mfma_f32_16x16x32_bf16(af0, bf, acc[0][nt], 0, 0, 0);
      acc[1][nt] = __builtin_amdgcn_mfma_f32_16x16x32_bf16(af1, bf, acc[1][nt], 0, 0, 0);
    }
  }
#pragma unroll
  for (int mt = 0; mt < 2; ++mt) {
    const int row0 = m0 + wave * 32 + mt * 16 + quad * 4;
#pragma unroll
    for (int r = 0; r < 4; ++r) {
      int row = row0 + r;
      if (row < M) {
        unsigned short* orow = h1b + (size_t)row * HD + l15;
#pragma unroll
        for (int nt = 0; nt < 8; ++nt) orow[nt * 16] = f2bf(acc[mt][nt][r]);
      }
    }
  }
}

// ---------------- agg1: wave/node, 4-edge unroll, bf16 gather, bf16 h out ----------------

__global__ __launch_bounds__(256) void agg1_kernel(const unsigned int* __restrict__ h1b,
                                                   const float* __restrict__ b1,
                                                   const float* __restrict__ dm,
                                                   const int* __restrict__ off,
                                                   const int* __restrict__ cnt,
                                                   const int2* __restrict__ sew,
                                                   unsigned int* __restrict__ hbf, int N) {
  const int wave = threadIdx.x >> 6;
  const int lane = threadIdx.x & 63;
  const int node = blockIdx.x * 4 + wave;
  if (node >= N) return;
  const int start = off[node];
  const int deg   = cnt[node];
  const int2* ep  = sew + start;

  float a0 = 0.f, a1 = 0.f, c0 = 0.f, c1 = 0.f;
  int e = 0;
  for (; e + 4 <= deg; e += 4) {
    int2 p0 = ep[e + 0];
    int2 p1 = ep[e + 1];
    int2 p2 = ep[e + 2];
    int2 p3 = ep[e + 3];
    unsigned int v0 = h1b[(size_t)p0.x * 64 + lane];
    unsigned int v1 = h1b[(size_t)p1.x * 64 + lane];
    unsigned int v2 = h1b[(size_t)p2.x * 64 + lane];
    unsigned int v3 = h1b[(size_t)p3.x * 64 + lane];
    float w0 = __int_as_float(p0.y), w1 = __int_as_float(p1.y);
    float w2 = __int_as_float(p2.y), w3 = __int_as_float(p3.y);
    a0 = fmaf(bf_lo(v0), w0, a0); a1 = fmaf(bf_hi(v0), w0, a1);
    c0 = fmaf(bf_lo(v1), w1, c0); c1 = fmaf(bf_hi(v1), w1, c1);
    a0 = fmaf(bf_lo(v2), w2, a0); a1 = fmaf(bf_hi(v2), w2, a1);
    c0 = fmaf(bf_lo(v3), w3, c0); c1 = fmaf(bf_hi(v3), w3, c1);
  }
  for (; e < deg; ++e) {
    int2 p = ep[e];
    unsigned int v = h1b[(size_t)p.x * 64 + lane];
    float w = __int_as_float(p.y);
    a0 = fmaf(bf_lo(v), w, a0); a1 = fmaf(bf_hi(v), w, a1);
  }
  a0 += c0; a1 += c1;

  const int f0 = lane * 2;
  float2 bb = *(const float2*)(b1 + f0);
  float2 dd = *(const float2*)(dm + (size_t)node * HD + f0);
  float r0 = fmaxf(a0 + bb.x, 0.f) * ((dd.x >= 0.5f) ? 2.0f : 0.0f);
  float r1 = fmaxf(a1 + bb.y, 0.f) * ((dd.y >= 0.5f) ? 2.0f : 0.0f);
  hbf[(size_t)node * 64 + lane] = (unsigned int)f2bf(r0) | ((unsigned int)f2bf(r1) << 16);
}

// ---------------- GEMM2 (MFMA bf16): h2b[M,64](bf16) = h_bf[M,128] @ W2 ----------------
// 128x64 tile / 256-thr block. Wave w: rows [32w,32w+32) = 2 m-tiles x 4 n-tiles.
// B staging: 4 threads/row x uint4 (8 ushorts) = 32 = BK.  (R4 bug: was uint2.)

__global__ __launch_bounds__(256) void gemm2_mfma(const unsigned short* __restrict__ hbf,
                                                  const unsigned short* __restrict__ w2t,
                                                  unsigned short* __restrict__ h2b, int M) {
  __shared__ unsigned short As[128][40];
  __shared__ unsigned short Bs[64][40];
  const int t    = threadIdx.x;
  const int wave = t >> 6;
  const int lane = t & 63;
  const int l15  = lane & 15;
  const int quad = lane >> 4;
  const int m0   = blockIdx.x * 128;

  const int sr = t >> 1;        // A staging row 0..127
  const int sk = (t & 1) * 16;
  const int rb = t >> 2;        // B staging row 0..63
  const int kb = (t & 3) * 8;   // 4 threads x 8 ushorts = 32

  const bool aok = (m0 + sr) < M;
  const unsigned short* arow = hbf + (size_t)(m0 + sr) * HD + sk;
  const unsigned short* brow = w2t + (size_t)rb * HD + kb;

  f32x4 acc[2][4];
#pragma unroll
  for (int i = 0; i < 2; ++i)
#pragma unroll
    for (int j = 0; j < 4; ++j) acc[i][j] = (f32x4)0.f;

  for (int k0 = 0; k0 < HD; k0 += 32) {
    uint4 av0 = make_uint4(0, 0, 0, 0), av1 = av0;
    if (aok) {
      av0 = *(const uint4*)(arow + k0);
      av1 = *(const uint4*)(arow + k0 + 8);
    }
    uint4 bv = *(const uint4*)(brow + k0);   // 8 ushorts
    __syncthreads();
    *(uint4*)&As[sr][sk]     = av0;
    *(uint4*)&As[sr][sk + 8] = av1;
    *(uint4*)&Bs[rb][kb]     = bv;
    __syncthreads();
    short8 af0 = *(const short8*)&As[wave * 32 + l15][quad * 8];
    short8 af1 = *(const short8*)&As[wave * 32 + 16 + l15][quad * 8];
#pragma unroll
    for (int nt = 0; nt < 4; ++nt) {
      short8 bf = *(const short8*)&Bs[nt * 16 + l15][quad * 8];
      acc[0][nt] = __builtin_amdgcn_mfma_f32_16x16x32_bf16(af0, bf, acc[0][nt], 0, 0, 0);
      acc[1][nt] = __builtin_amdgcn_mfma_f32_16x16x32_bf16(af1, bf, acc[1][nt], 0, 0, 0);
    }
  }
#pragma unroll
  for (int mt = 0; mt < 2; ++mt) {
    const int row0 = m0 + wave * 32 + mt * 16 + quad * 4;
#pragma unroll
    for (int r = 0; r < 4; ++r) {
      int row = row0 + r;
      if (row < M) {
        unsigned short* orow = h2b + (size_t)row * CD + l15;
#pragma unroll
        for (int nt = 0; nt < 4; ++nt) orow[nt * 16] = f2bf(acc[mt][nt][r]);
      }
    }
  }
}

// ---------------- agg2 + bias + log_softmax: wave/node, bf16 gather ----------------

__global__ __launch_bounds__(256) void agg2_kernel(const unsigned short* __restrict__ h2b,
                                                   const float* __restrict__ b2,
                                                   const int* __restrict__ off,
                                                   const int* __restrict__ cnt,
                                                   const int2* __restrict__ sew,
                                                   float* __restrict__ out, int N) {
  const int wave = threadIdx.x >> 6;
  const int c    = threadIdx.x & 63;
  const int node = blockIdx.x * 4 + wave;
  if (node >= N) return;
  const int start = off[node];
  const int deg   = cnt[node];
  const int2* ep  = sew + start;

  float acc = b2[c], acc2 = 0.f;
  int e = 0;
  for (; e + 4 <= deg; e += 4) {
    int2 p0 = ep[e + 0];
    int2 p1 = ep[e + 1];
    int2 p2 = ep[e + 2];
    int2 p3 = ep[e + 3];
    float v0 = bf1(h2b[(size_t)p0.x * CD + c]);
    float v1 = bf1(h2b[(size_t)p1.x * CD + c]);
    float v2 = bf1(h2b[(size_t)p2.x * CD + c]);
    float v3 = bf1(h2b[(size_t)p3.x * CD + c]);
    acc  = fmaf(v0, __int_as_float(p0.y), acc);
    acc2 = fmaf(v1, __int_as_float(p1.y), acc2);
    acc  = fmaf(v2, __int_as_float(p2.y), acc);
    acc2 = fmaf(v3, __int_as_float(p3.y), acc2);
  }
  for (; e < deg; ++e) {
    int2 p = ep[e];
    acc = fmaf(bf1(h2b[(size_t)p.x * CD + c]), __int_as_float(p.y), acc);
  }
  acc += acc2;

  float m = acc;
#pragma unroll
  for (int o = 32; o > 0; o >>= 1) m = fmaxf(m, __shfl_xor(m, o, 64));
  float ex = __expf(acc - m);
  float ssum = ex;
#pragma unroll
  for (int o = 32; o > 0; o >>= 1) ssum += __shfl_xor(ssum, o, 64);
  out[(size_t)node * CD + c] = (acc - m) - __logf(ssum);
}

// ---------------- launch ----------------

extern "C" void kernel_launch(void* const* d_in, const int* in_sizes, int n_in,
                              void* d_out, int out_size, void* d_ws, size_t ws_size,
                              hipStream_t stream) {
  const float* x  = (const float*)d_in[0];
  const float* ew = (const float*)d_in[1];
  const float* W1 = (const float*)d_in[2];
  const float* b1 = (const float*)d_in[3];
  const float* W2 = (const float*)d_in[4];
  const float* b2 = (const float*)d_in[5];
  const float* dm = (const float*)d_in[6];
  const int*   ei = (const int*)d_in[7];
  float* out = (float*)d_out;

  const int E = in_sizes[1];
  const int N = in_sizes[6] / HD;
  const int* srcp = ei;
  const int* dstp = ei + E;
  const int nb = (N + 2047) / 2048;

  uint8_t* w = (uint8_t*)d_ws;
  size_t o = 0;
  auto alloc = [&](size_t bytes) -> void* {
    void* p = w + o;
    o = (o + bytes + 255) & ~(size_t)255;
    return p;
  };
  int*   off  = (int*)alloc((size_t)N * 4);
  int*   cnt  = (int*)alloc((size_t)N * 4);
  int*   cur  = (int*)alloc((size_t)N * 4);
  int2*  sew  = (int2*)alloc((size_t)E * 8);
  unsigned short* h1b = (unsigned short*)alloc((size_t)N * HD * 2);
  unsigned int*   hbf = (unsigned int*)alloc((size_t)N * HD * 2);
  unsigned short* h2b = (unsigned short*)alloc((size_t)N * CD * 2);
  unsigned short* w1t = (unsigned short*)alloc((size_t)FIN * HD * 2);
  unsigned short* w2t = (unsigned short*)alloc((size_t)HD * CD * 2);
  int*   bsum = (int*)alloc((size_t)nb * 4);
  int*   boff = (int*)alloc((size_t)nb * 4);

  hipMemsetAsync(cnt, 0, (size_t)N * 4, stream);
  wprep<<<(FIN * HD + HD * CD + 255) / 256, 256, 0, stream>>>(W1, W2, w1t, w2t);
  hist_kernel<<<(E + 255) / 256, 256, 0, stream>>>(dstp, E, cnt);
  scan_a<<<nb, 256, 0, stream>>>(cnt, bsum, N);
  scan_b<<<1, 64, 0, stream>>>(bsum, boff, nb);
  scan_c<<<nb, 256, 0, stream>>>(cnt, boff, off, cur, N);
  scatter_kernel<<<(E + 255) / 256, 256, 0, stream>>>(srcp, dstp, ew, E, cur, sew);
  gemm1_mfma<<<(N + 127) / 128, 256, 0, stream>>>(x, w1t, h1b, N);
  agg1_kernel<<<(N + 3) / 4, 256, 0, stream>>>((const unsigned int*)h1b, b1, dm, off, cnt, sew, hbf, N);
  gemm2_mfma<<<(N + 127) / 128, 256, 0, stream>>>((const unsigned short*)hbf, w2t, h2b, N);
  agg2_kernel<<<(N + 3) / 4, 256, 0, stream>>>(h2b, b2, off, cnt, sew, out, N);
}